// Round 6
// baseline (255.538 us; speedup 1.0000x reference)
//
#include <hip/hip_runtime.h>
#include <hip/hip_bf16.h>

// Problem constants
#define NB 8
#define NH 8
#define LQ 1024
#define LK 1024
#define DD 64
#define EC 0.18033688011112042f      // (1/8) * log2(e)
#define OUT0_SIZE (8ull*8*1024*64)   // output [B,H,LQ,D]

typedef __bf16 bf16x8 __attribute__((ext_vector_type(8)));
typedef __bf16 bf16x4 __attribute__((ext_vector_type(4)));
typedef float  f32x4  __attribute__((ext_vector_type(4)));

static __device__ __forceinline__ __bf16 f2b(float f) {
    unsigned u = __builtin_bit_cast(unsigned, f);
    unsigned r = (u + 0x7fffu + ((u >> 16) & 1u)) >> 16;
    return __builtin_bit_cast(__bf16, (unsigned short)r);
}

// ---------------------------------------------------------------------------
// K-calib: pure linear NT write stream, 32 MB over the attn output region
// (fully overwritten by attn_kernel afterwards -> no correctness impact).
// Purpose: measure the chip's pure-write ceiling in this exact memory region.
// ---------------------------------------------------------------------------
__global__ __launch_bounds__(256) void calib_write(float* __restrict__ dst) {
    const f32x4 vv = {1.f, 1.f, 1.f, 1.f};
    size_t idx = ((size_t)blockIdx.x * 256 + threadIdx.x) * 4;
    const size_t stride = (size_t)2048 * 256 * 4;
    #pragma unroll
    for (int i = 0; i < 4; ++i)
        __builtin_nontemporal_store(vv, (f32x4*)&dst[idx + (size_t)i * stride]);
}

// ---------------------------------------------------------------------------
// K0a: independent 64x64x64 f32 products: P1=WA@WB, P2=WBt@WAt, Wv=Wav@Wbv
// ---------------------------------------------------------------------------
__global__ __launch_bounds__(256) void fold_pairs(
        const float* __restrict__ pWA, const float* __restrict__ pWB,
        const float* __restrict__ pWBt, const float* __restrict__ pWAt,
        const float* __restrict__ pWav, const float* __restrict__ pWbv,
        float* __restrict__ P1, float* __restrict__ P2, float* __restrict__ Wv) {
    __shared__ float AT[64*68];
    __shared__ float Bl[64*64];
    const int h = blockIdx.x / 3;
    const int which = blockIdx.x - h*3;
    const int t = threadIdx.x;
    const float *A, *B; float* C;
    if (which == 0)      { A = pWA  + h*4096; B = pWB  + h*4096; C = P1 + h*4096; }
    else if (which == 1) { A = pWBt + h*4096; B = pWAt + h*4096; C = P2 + h*4096; }
    else                 { A = pWav + h*4096; B = pWbv + h*4096; C = Wv + h*4096; }

    for (int i = t; i < 4096; i += 256) {
        int r = i >> 6, c = i & 63;
        AT[c*68 + r] = A[i];
        Bl[i] = B[i];
    }
    __syncthreads();
    const int r0 = (t >> 4) * 4, j0 = (t & 15) * 4;
    float acc[4][4] = {};
    #pragma unroll 8
    for (int k = 0; k < 64; ++k) {
        f32x4 a = *(const f32x4*)&AT[k*68 + r0];
        f32x4 b = *(const f32x4*)&Bl[k*64 + j0];
        #pragma unroll
        for (int i = 0; i < 4; ++i)
            #pragma unroll
            for (int j = 0; j < 4; ++j) acc[i][j] += a[i] * b[j];
    }
    #pragma unroll
    for (int i = 0; i < 4; ++i) {
        f32x4 o = { acc[i][0], acc[i][1], acc[i][2], acc[i][3] };
        *(f32x4*)&C[(r0 + i)*64 + j0] = o;
    }
}

// K0b: W = P1 @ P2, 8 blocks (one per head)
__global__ __launch_bounds__(256) void fold_final(
        const float* __restrict__ P1, const float* __restrict__ P2,
        float* __restrict__ Wout) {
    __shared__ float AT[64*68];
    __shared__ float Bl[64*64];
    const int h = blockIdx.x;
    const int t = threadIdx.x;
    for (int i = t; i < 4096; i += 256) {
        int r = i >> 6, c = i & 63;
        AT[c*68 + r] = P1[h*4096 + i];
        Bl[i] = P2[h*4096 + i];
    }
    __syncthreads();
    const int r0 = (t >> 4) * 4, j0 = (t & 15) * 4;
    float acc[4][4] = {};
    #pragma unroll 8
    for (int k = 0; k < 64; ++k) {
        f32x4 a = *(const f32x4*)&AT[k*68 + r0];
        f32x4 b = *(const f32x4*)&Bl[k*64 + j0];
        #pragma unroll
        for (int i = 0; i < 4; ++i)
            #pragma unroll
            for (int j = 0; j < 4; ++j) acc[i][j] += a[i] * b[j];
    }
    #pragma unroll
    for (int i = 0; i < 4; ++i) {
        f32x4 o = { acc[i][0], acc[i][1], acc[i][2], acc[i][3] };
        *(f32x4*)&Wout[h*4096 + (r0 + i)*64 + j0] = o;
    }
}

// ---------------------------------------------------------------------------
// K1 (merged prepass): blockIdx.y selects qW / qtT / vWT production
// ---------------------------------------------------------------------------
__global__ __launch_bounds__(256) void prepass(
        const float* __restrict__ q, const float* __restrict__ W,
        const float* __restrict__ qt, const float* __restrict__ v,
        const float* __restrict__ Wv,
        __bf16* __restrict__ qW, __bf16* __restrict__ qtT,
        __bf16* __restrict__ vWT) {
    __shared__ float smem[8448];
    const int bh = blockIdx.x;
    const int by = blockIdx.y;
    const int batch = bh >> 3, h = bh & 7;
    const int t = threadIdx.x;

    if (by < 16) {
        float* qT = smem;            // [c][r] 64x68
        float* Wl = smem + 4352;     // [c][j] 64x64
        const int a0 = by * 64;
        for (int i = t; i < 4096; i += 256) {
            int r = i >> 6, c = i & 63;
            Wl[i] = W[h*4096 + i];
            qT[c*68 + r] = q[(((size_t)batch*LQ + a0 + r)*NH + h)*DD + c];
        }
        __syncthreads();
        const int r0 = (t >> 4) * 4, j0 = (t & 15) * 4;
        float acc[4][4] = {};
        #pragma unroll 8
        for (int c = 0; c < 64; ++c) {
            f32x4 a = *(const f32x4*)&qT[c*68 + r0];
            f32x4 b = *(const f32x4*)&Wl[c*64 + j0];
            #pragma unroll
            for (int i = 0; i < 4; ++i)
                #pragma unroll
                for (int j = 0; j < 4; ++j) acc[i][j] += a[i] * b[j];
        }
        #pragma unroll
        for (int i = 0; i < 4; ++i) {
            bf16x4 o;
            #pragma unroll
            for (int j = 0; j < 4; ++j) o[j] = f2b(acc[i][j]);
            *(bf16x4*)&qW[((size_t)bh*LQ + a0 + r0 + i)*DD + j0] = o;
        }
    } else if (by < 24) {
        float* tile = smem;          // [j][n] 64x132
        const int n0 = (by - 16) * 128;
        #pragma unroll
        for (int it = 0; it < 8; ++it) {
            int idx = (t + 256*it) * 4;
            int j = idx >> 7, n = idx & 127;
            *(f32x4*)&tile[j*132 + n] = *(const f32x4*)&qt[((size_t)bh*DD + j)*LK + n0 + n];
        }
        __syncthreads();
        const int j0 = (t & 15) * 4;
        #pragma unroll
        for (int it = 0; it < 8; ++it) {
            int n = (t >> 4) + 16*it;
            bf16x4 o;
            #pragma unroll
            for (int i = 0; i < 4; ++i) o[i] = f2b(tile[(j0 + i)*132 + n]);
            *(bf16x4*)&qtT[((size_t)bh*LK + n0 + n)*DD + j0] = o;
        }
    } else {
        float* vT  = smem;           // [n][m] 64x68
        float* Wvl = smem + 4352;    // [n][c] 64x64
        const int mb0 = (by - 24) * 64;
        for (int i = t; i < 4096; i += 256) {
            int r = i >> 6, c = i & 63;     // r = m-row, c = n
            Wvl[i] = Wv[h*4096 + i];
            vT[c*68 + r] = v[(((size_t)batch*LK + mb0 + r)*NH + h)*DD + c];
        }
        __syncthreads();
        const int c0 = (t >> 4) * 4, m0 = (t & 15) * 4;
        float acc[4][4] = {};               // [c][m]
        #pragma unroll 8
        for (int n = 0; n < 64; ++n) {
            f32x4 wv = *(const f32x4*)&Wvl[n*64 + c0];
            f32x4 vv = *(const f32x4*)&vT[n*68 + m0];
            #pragma unroll
            for (int ci = 0; ci < 4; ++ci)
                #pragma unroll
                for (int mi = 0; mi < 4; ++mi) acc[ci][mi] += wv[ci] * vv[mi];
        }
        #pragma unroll
        for (int ci = 0; ci < 4; ++ci) {
            bf16x4 o;
            #pragma unroll
            for (int mi = 0; mi < 4; ++mi) o[mi] = f2b(acc[ci][mi]);
            *(bf16x4*)&vWT[((size_t)bh*DD + c0 + ci)*LK + mb0 + m0] = o;
        }
    }
}

// ---------------------------------------------------------------------------
// K4: fused scores + softmax + PV; ALL attn stores deferred to a final
// linear sweep. Block stages its full 32x1024 f32 P tile in LDS (128 KB,
// 1 block/CU); after compute, each wave NT-streams 8 complete rows
// (32 KB contiguous) -> long linear per-wave HBM write streams.
// LDS: Pbig 131584 B + Elds 9216 + Obuf 8704 + rsumbuf 256 = 149760 B.
// ---------------------------------------------------------------------------
__global__ __launch_bounds__(256) void attn_kernel(
        const __bf16* __restrict__ qW, const __bf16* __restrict__ qtT,
        const __bf16* __restrict__ vWT, float* __restrict__ out) {
    extern __shared__ __align__(16) char smem_raw[];
    float*  Pbig    = (float*)smem_raw;                        // [32][1028]
    __bf16* Elds    = (__bf16*)(smem_raw + 131584);            // [4][16][72]
    float*  Obuf    = (float*)(smem_raw + 131584 + 9216);      // [32][68]
    float*  rsumbuf = (float*)(smem_raw + 131584 + 9216 + 8704); // [2][2][16]

    const int bid = blockIdx.x;
    const int xcd = bid & 7, s = bid >> 3;
    const int bh  = xcd * 8 + (s >> 5);
    const int a0  = (s & 31) * 32;
    const int t   = threadIdx.x;
    const int w   = t >> 6, l = t & 63;
    const int lg  = l & 15, g = l >> 4;
    const int strip = w & 1, nh = w >> 1;
    const int qbase = a0 + strip * 16;
    const int n0w   = nh * 512;

    const __bf16* qtb = qtT + (size_t)bh * LK * DD;
    const __bf16* vwb = vWT + (size_t)bh * DD * LK;

    // B fragments (N = q): lane holds qW[qbase+lg][g*8 .. +7] (+32 for k-hi)
    const bf16x8* qWp = reinterpret_cast<const bf16x8*>(qW + ((size_t)bh*LQ + qbase + lg)*DD);
    bf16x8 bfrag0 = qWp[g];
    bf16x8 bfrag1 = qWp[g + 4];

    // ---- pass 1: per-q row sums of exp(S) over this wave's 512 keys ----
    bf16x8 ka[4][2];
    #pragma unroll
    for (int sub = 0; sub < 4; ++sub) {
        const bf16x8* qtp = (const bf16x8*)(qtb + (size_t)(n0w + sub*16 + lg)*DD);
        ka[sub][0] = qtp[g]; ka[sub][1] = qtp[g + 4];
    }
    float rsum = 0.f;
    #pragma unroll
    for (int nc = 0; nc < 8; ++nc) {
        f32x4 accs[4];
        #pragma unroll
        for (int sub = 0; sub < 4; ++sub) {
            f32x4 acc = {0.f, 0.f, 0.f, 0.f};
            acc = __builtin_amdgcn_mfma_f32_16x16x32_bf16(ka[sub][0], bfrag0, acc, 0, 0, 0);
            acc = __builtin_amdgcn_mfma_f32_16x16x32_bf16(ka[sub][1], bfrag1, acc, 0, 0, 0);
            accs[sub] = acc;
        }
        if (nc < 7) {
            #pragma unroll
            for (int sub = 0; sub < 4; ++sub) {
                const bf16x8* qtp = (const bf16x8*)(qtb + (size_t)(n0w + (nc+1)*64 + sub*16 + lg)*DD);
                ka[sub][0] = qtp[g]; ka[sub][1] = qtp[g + 4];
            }
        }
        #pragma unroll
        for (int sub = 0; sub < 4; ++sub)
            #pragma unroll
            for (int r = 0; r < 4; ++r) rsum += __builtin_exp2f(accs[sub][r] * EC);
    }
    rsum += __shfl_xor(rsum, 16);
    rsum += __shfl_xor(rsum, 32);
    if (l < 16) rsumbuf[(nh*2 + strip)*16 + l] = rsum;
    __syncthreads();
    const float rinv = 1.0f / (rsumbuf[(0*2 + strip)*16 + lg] + rsumbuf[(1*2 + strip)*16 + lg]);

    // ---- pass 2: P compute into LDS (Pbig f32 + Elds bf16) + PV ----
    #pragma unroll
    for (int sub = 0; sub < 4; ++sub) {
        const bf16x8* qtp = (const bf16x8*)(qtb + (size_t)(n0w + sub*16 + lg)*DD);
        ka[sub][0] = qtp[g]; ka[sub][1] = qtp[g + 4];
    }
    bf16x8 vp0[4], vp1[4];
    #pragma unroll
    for (int ct = 0; ct < 4; ++ct) {
        const bf16x8* vpp = (const bf16x8*)(vwb + (size_t)(ct*16 + lg)*LK + n0w);
        vp0[ct] = vpp[g]; vp1[ct] = vpp[4 + g];
    }

    f32x4 oacc[4];
    #pragma unroll
    for (int ct = 0; ct < 4; ++ct) oacc[ct] = f32x4{0.f, 0.f, 0.f, 0.f};

    __bf16* eldsw = Elds + w * (16*72);
    const int prow = strip*16 + lg;                 // Pbig row for this lane

    #pragma unroll
    for (int nc = 0; nc < 8; ++nc) {
        const int nbase = n0w + nc*64;
        #pragma unroll
        for (int sub = 0; sub < 4; ++sub) {
            f32x4 acc = {0.f, 0.f, 0.f, 0.f};
            acc = __builtin_amdgcn_mfma_f32_16x16x32_bf16(ka[sub][0], bfrag0, acc, 0, 0, 0);
            acc = __builtin_amdgcn_mfma_f32_16x16x32_bf16(ka[sub][1], bfrag1, acc, 0, 0, 0);
            f32x4 p; bf16x4 pb;
            #pragma unroll
            for (int r = 0; r < 4; ++r) {
                float pv_ = __builtin_exp2f(acc[r] * EC) * rinv;
                p[r] = pv_;
                pb[r] = f2b(pv_);
            }
            *(f32x4*)&Pbig[prow*1028 + nbase + sub*16 + g*4] = p;
            *(bf16x4*)&eldsw[lg*72 + sub*16 + g*4] = pb;
        }
        // prefetch next chunk's QK fragments
        if (nc < 7) {
            #pragma unroll
            for (int sub = 0; sub < 4; ++sub) {
                const bf16x8* qtp = (const bf16x8*)(qtb + (size_t)(nbase + 64 + sub*16 + lg)*DD);
                ka[sub][0] = qtp[g]; ka[sub][1] = qtp[g + 4];
            }
        }
        // PV with current vWT fragments
        bf16x8 pf0 = ((const bf16x8*)&eldsw[lg*72])[g];
        bf16x8 pf1 = ((const bf16x8*)&eldsw[lg*72])[4 + g];
        #pragma unroll
        for (int ct = 0; ct < 4; ++ct) {
            oacc[ct] = __builtin_amdgcn_mfma_f32_16x16x32_bf16(vp0[ct], pf0, oacc[ct], 0, 0, 0);
            oacc[ct] = __builtin_amdgcn_mfma_f32_16x16x32_bf16(vp1[ct], pf1, oacc[ct], 0, 0, 0);
        }
        if (nc < 7) {
            #pragma unroll
            for (int ct = 0; ct < 4; ++ct) {
                const bf16x8* vpp = (const bf16x8*)(vwb + (size_t)(ct*16 + lg)*LK + nbase + 64);
                vp0[ct] = vpp[g]; vp1[ct] = vpp[4 + g];
            }
        }
    }

    // ---- cross-wave O reduction into Obuf ----
    if (nh == 1) {
        #pragma unroll
        for (int ct = 0; ct < 4; ++ct)
            *(f32x4*)&Obuf[(strip*16 + lg)*68 + ct*16 + g*4] = oacc[ct];
    }
    __syncthreads();
    if (nh == 0) {
        #pragma unroll
        for (int ct = 0; ct < 4; ++ct) {
            f32x4 o = *(const f32x4*)&Obuf[(strip*16 + lg)*68 + ct*16 + g*4];
            o = o + oacc[ct];
            *(f32x4*)&Obuf[(strip*16 + lg)*68 + ct*16 + g*4] = o;
        }
    }
    __syncthreads();

    // ---- final linear NT sweeps ----
    // attn: wave w streams rows [a0+w*8, a0+w*8+8) = 32 KB contiguous
    float* attnrow = out + OUT0_SIZE + ((size_t)bh << 20) + ((size_t)(a0 + w*8) << 10);
    #pragma unroll 4
    for (int i = 0; i < 32; ++i) {
        int row = i >> 2;
        int col = (i & 3) * 256 + l * 4;
        f32x4 pvec = *(const f32x4*)&Pbig[(w*8 + row)*1028 + col];
        __builtin_nontemporal_store(pvec, (f32x4*)&attnrow[((size_t)row << 10) + col]);
    }
    // out: block streams 8 KB contiguous
    #pragma unroll
    for (int it = 0; it < 2; ++it) {
        int off = it*1024 + t*4;
        int row = off >> 6, col = off & 63;
        f32x4 o = *(const f32x4*)&Obuf[row*68 + col];
        __builtin_nontemporal_store(o, (f32x4*)&out[(((size_t)bh*LQ + a0) << 6) + off]);
    }
}

// ---------------------------------------------------------------------------
extern "C" void kernel_launch(void* const* d_in, const int* in_sizes, int n_in,
                              void* d_out, int out_size, void* d_ws, size_t ws_size,
                              hipStream_t stream) {
    const float* q   = (const float*)d_in[0];
    const float* WA  = (const float*)d_in[1];
    const float* WB  = (const float*)d_in[2];
    const float* WAt = (const float*)d_in[3];
    const float* WBt = (const float*)d_in[4];
    const float* Wav = (const float*)d_in[5];
    const float* Wbv = (const float*)d_in[6];
    const float* qt  = (const float*)d_in[7];
    const float* v   = (const float*)d_in[8];
    float* out = (float*)d_out;

    char* ws = (char*)d_ws;
    float*  W    = (float*)(ws);                          // 128 KB
    float*  Wv   = (float*)(ws + 131072);                 // 128 KB
    __bf16* qW   = (__bf16*)(ws + 262144);                // 8 MB
    __bf16* qtT  = (__bf16*)(ws + 262144 + 8388608);      // 8 MB
    __bf16* vWT  = (__bf16*)(ws + 262144 + 2*8388608);    // 8 MB
    // P1/P2 alias the qW region: consumed by fold_final before prepass writes.
    float*  P1   = (float*)(ws + 262144);                 // 128 KB
    float*  P2   = (float*)(ws + 262144 + 131072);        // 128 KB

    // calibration: pure 32MB linear NT write into attn region (overwritten later)
    hipLaunchKernelGGL(calib_write, dim3(2048), dim3(256), 0, stream, out + OUT0_SIZE);

    hipLaunchKernelGGL(fold_pairs, dim3(24), dim3(256), 0, stream,
                       WA, WB, WBt, WAt, Wav, Wbv, P1, P2, Wv);
    hipLaunchKernelGGL(fold_final, dim3(8),  dim3(256), 0, stream, P1, P2, W);
    hipLaunchKernelGGL(prepass,    dim3(64, 40), dim3(256), 0, stream,
                       q, W, qt, v, Wv, qW, qtT, vWT);
    hipLaunchKernelGGL(attn_kernel, dim3(2048), dim3(256), 149760, stream,
                       qW, qtT, vWT, out);
}